// Round 10
// baseline (401.419 us; speedup 1.0000x reference)
//
#include <hip/hip_runtime.h>
#include <hip/hip_bf16.h>

#define HIDDEN 8192
#define NHEADS 64
#define NKV 8
#define HD 128
#define BATCH 32
#define PADLEN 2048
#define NCHUNK 8
#define CHUNKLEN 256

using bf16x8 = __attribute__((ext_vector_type(8))) short;
using f32x4 = __attribute__((ext_vector_type(4))) float;

// ---------------------------------------------------------------------------
// helpers
// ---------------------------------------------------------------------------
__device__ __forceinline__ void gld16(const float* g, float* l) {
    __builtin_amdgcn_global_load_lds(
        (const __attribute__((address_space(1))) void*)g,
        (__attribute__((address_space(3))) void*)l,
        16, 0, 0);
}

// readlane for float: bitcast, NOT value conversion (builtin is (uint,uint)!)
__device__ __forceinline__ float readlane_f(float v, int lane) {
    return __uint_as_float(__builtin_amdgcn_readlane(__float_as_uint(v), lane));
}

__device__ __forceinline__ short f2bf(float f) {      // RNE f32->bf16
    unsigned u = __float_as_uint(f);
    u += 0x7fff + ((u >> 16) & 1);
    return (short)(u >> 16);
}
__device__ __forceinline__ float bf2f(short s) {
    return __uint_as_float(((unsigned)(unsigned short)s) << 16);
}

// ---------------------------------------------------------------------------
// split a f32 vector into hi/lo bf16 (x = hi + lo, residual ~2^-17 rel)
// ---------------------------------------------------------------------------
__global__ __launch_bounds__(256) void cvt_split(const float* __restrict__ in,
                                                 short* __restrict__ hi,
                                                 short* __restrict__ lo, int n4) {
    int i = blockIdx.x * 256 + threadIdx.x;
    if (i >= n4) return;
    float4 v = ((const float4*)in)[i];
    short4 h, l;
    h.x = f2bf(v.x); l.x = f2bf(v.x - bf2f(h.x));
    h.y = f2bf(v.y); l.y = f2bf(v.y - bf2f(h.y));
    h.z = f2bf(v.z); l.z = f2bf(v.z - bf2f(h.z));
    h.w = f2bf(v.w); l.w = f2bf(v.w - bf2f(h.w));
    ((short4*)hi)[i] = h;
    ((short4*)lo)[i] = l;
}

// ---------------------------------------------------------------------------
// MFMA split-bf16 skinny GEMM v3 — occupancy-first.
// Wave covers 16 cols (1 n-tile); acc 8 VGPR, A-frags 16, B 8 -> ~65 VGPR
// => 6+ waves/SIMD (launch_bounds(256,6)); latency hidden by TLP + compiler
// hoisting across the fully-unrolled k-loop (no manual prefetch copies —
// those forced an end-of-iteration wait and regressed, r9).
// QKV grid: 160 cb x 16 kb = 2560 blocks (10/CU); wo: 128 x 16 (8/CU).
// ---------------------------------------------------------------------------
#define QSEC 262144          // 32*8192
#define KSEC 294912          // QSEC + 32*1024
#define QKV_STRIDE 327680    // QSEC + 2*32*1024
#define NSPLIT 16
#define KSLICE 512           // HIDDEN / NSPLIT

__global__ __launch_bounds__(256, 6) void gemm_mfma(
        const short* __restrict__ xhi, const short* __restrict__ xlo,
        const float* __restrict__ W0, const float* __restrict__ W1,
        const float* __restrict__ W2, float* __restrict__ P, size_t pstride) {
    const int tid = threadIdx.x;
    const int wv = tid >> 6, ln = tid & 63;
    const int cb = blockIdx.x, kb = blockIdx.y;

    const float* W; int N2; size_t so; int nbase;
    if (cb < 128)      { W = W0; N2 = 8192; so = 0;    nbase = cb * 64; }
    else if (cb < 144) { W = W1; N2 = 1024; so = QSEC; nbase = (cb - 128) * 64; }
    else               { W = W2; N2 = 1024; so = KSEC; nbase = (cb - 144) * 64; }

    const int n0 = nbase + wv * 16;      // this wave: cols n0..n0+15
    const int lrow = ln & 15;
    const int kgrp = ln >> 4;
    const int k0 = kb * KSLICE;

    const float* wp = W + (size_t)(k0 + kgrp * 8) * N2 + (n0 + lrow);
    const short* xh0 = xhi + (size_t)lrow * HIDDEN + k0 + kgrp * 8;
    const short* xl0 = xlo + (size_t)lrow * HIDDEN + k0 + kgrp * 8;
    const short* xh1 = xh0 + (size_t)16 * HIDDEN;
    const short* xl1 = xl0 + (size_t)16 * HIDDEN;

    f32x4 acc0 = {0.f,0.f,0.f,0.f}, acc1 = {0.f,0.f,0.f,0.f};

#pragma unroll
    for (int kk = 0; kk < KSLICE; kk += 32) {
        float b[8];
#pragma unroll
        for (int j = 0; j < 8; ++j) b[j] = wp[(size_t)(kk + j) * N2];
        bf16x8 a0h = *(const bf16x8*)(xh0 + kk);
        bf16x8 a0l = *(const bf16x8*)(xl0 + kk);
        bf16x8 a1h = *(const bf16x8*)(xh1 + kk);
        bf16x8 a1l = *(const bf16x8*)(xl1 + kk);

        bf16x8 bh, bl;
#pragma unroll
        for (int j = 0; j < 8; ++j) {
            short h = f2bf(b[j]);
            bh[j] = h;
            bl[j] = f2bf(b[j] - bf2f(h));
        }
        acc0 = __builtin_amdgcn_mfma_f32_16x16x32_bf16(a0h, bh, acc0, 0, 0, 0);
        acc1 = __builtin_amdgcn_mfma_f32_16x16x32_bf16(a1h, bh, acc1, 0, 0, 0);
        acc0 = __builtin_amdgcn_mfma_f32_16x16x32_bf16(a0l, bh, acc0, 0, 0, 0);
        acc1 = __builtin_amdgcn_mfma_f32_16x16x32_bf16(a1l, bh, acc1, 0, 0, 0);
        acc0 = __builtin_amdgcn_mfma_f32_16x16x32_bf16(a0h, bl, acc0, 0, 0, 0);
        acc1 = __builtin_amdgcn_mfma_f32_16x16x32_bf16(a1h, bl, acc1, 0, 0, 0);
    }

    // C/D: col = l&15, row = (l>>4)*4 + reg (m89-verified)
    float* pb = P + (size_t)kb * pstride + so;
#pragma unroll
    for (int r = 0; r < 4; ++r) {
        int row = kgrp * 4 + r;
        pb[(size_t)row * N2 + n0 + lrow]        = acc0[r];
        pb[(size_t)(row + 16) * N2 + n0 + lrow] = acc1[r];
    }
}

// out[i] = sum_s P[s][i]  (NSPLIT k-split partials) — used for wo only
__global__ __launch_bounds__(256) void reduce_split(const float* __restrict__ P,
                                                    float* __restrict__ out,
                                                    int nelem, size_t pstride) {
    int i = (blockIdx.x * 256 + threadIdx.x) * 4;
    if (i >= nelem) return;
    float4 a = *(const float4*)(P + i);
#pragma unroll 4
    for (int s = 1; s < NSPLIT; ++s) {
        float4 b = *(const float4*)(P + (size_t)s * pstride + i);
        a.x += b.x; a.y += b.y; a.z += b.z; a.w += b.w;
    }
    *(float4*)(out + i) = a;
}

// ---------------------------------------------------------------------------
// Fused reduce(QKV partials) + rotary.
// Blocks 0..143: rot rows (q: 0..2047, k: 2048..2303) -> qr_buf/kr_buf.
// Blocks 144..159: v rows (256) -> v_buf (reduce only).
// ---------------------------------------------------------------------------
#define RROWS 16
__global__ __launch_bounds__(128) void reduce_rotary(const float* __restrict__ P,
                                                     const float* __restrict__ rot,
                                                     float* __restrict__ qout,
                                                     float* __restrict__ kout,
                                                     float* __restrict__ vout) {
    __shared__ float rows[RROWS][HD];
    const int tid = threadIdx.x;
    const int blk = blockIdx.x;

    if (blk < 144) {
        const int row0 = blk * RROWS;
        for (int i = tid; i < RROWS * HD; i += 128) {
            int r = row0 + (i >> 7);
            int d = i & 127;
            size_t off;
            if (r < BATCH * NHEADS) off = (size_t)(r >> 6) * 8192 + (r & 63) * 128 + d;
            else {
                int r2 = r - BATCH * NHEADS;
                off = QSEC + (size_t)(r2 >> 3) * 1024 + (r2 & 7) * 128 + d;
            }
            float a = P[off];
#pragma unroll 5
            for (int s = 1; s < NSPLIT; ++s) a += P[(size_t)s * QKV_STRIDE + off];
            rows[i >> 7][d] = a;
        }
        __syncthreads();

        float acc[RROWS];
#pragma unroll
        for (int r = 0; r < RROWS; ++r) acc[r] = 0.f;
        for (int d4 = 0; d4 < HD; d4 += 4) {
            float r0 = rot[(size_t)(d4 + 0) * HD + tid];
            float r1 = rot[(size_t)(d4 + 1) * HD + tid];
            float r2 = rot[(size_t)(d4 + 2) * HD + tid];
            float r3 = rot[(size_t)(d4 + 3) * HD + tid];
#pragma unroll
            for (int r = 0; r < RROWS; ++r) {
                float4 xv = *(const float4*)&rows[r][d4];
                acc[r] = fmaf(xv.x, r0, acc[r]);
                acc[r] = fmaf(xv.y, r1, acc[r]);
                acc[r] = fmaf(xv.z, r2, acc[r]);
                acc[r] = fmaf(xv.w, r3, acc[r]);
            }
        }
#pragma unroll
        for (int r = 0; r < RROWS; ++r) {
            int gr = row0 + r;
            float* dst = (gr < BATCH * NHEADS)
                             ? (qout + (size_t)gr * HD)
                             : (kout + (size_t)(gr - BATCH * NHEADS) * HD);
            dst[tid] = acc[r];
        }
    } else {
        const int row0 = (blk - 144) * RROWS;     // 0..255
        for (int i = tid; i < RROWS * HD; i += 128) {
            int r2 = row0 + (i >> 7);
            int d = i & 127;
            size_t off = KSEC + (size_t)(r2 >> 3) * 1024 + (r2 & 7) * 128 + d;
            float a = P[off];
#pragma unroll 5
            for (int s = 1; s < NSPLIT; ++s) a += P[(size_t)s * QKV_STRIDE + off];
            vout[(size_t)r2 * HD + d] = a;
        }
    }
}

// ---------------------------------------------------------------------------
// Flash-decode attention, split-KV x8, counted-vmcnt ring (T4).
// Same r5-proven structure (K+V staged, TILE=16, NBUF=4, vmcnt(4) depth-2);
// NCHUNK 4->8 gives 2048 blocks = 8 slots/CU for cross-block latency cover.
// ---------------------------------------------------------------------------
#define TILE 16
#define NBUF 4
__global__ __launch_bounds__(512, 4) void attn_decode(
        const float* __restrict__ qr, const float* __restrict__ kr,
        const float* __restrict__ vnew, const float* __restrict__ kcache,
        const float* __restrict__ vcache, const int* __restrict__ sp_ptr,
        float* __restrict__ part_acc, float* __restrict__ part_md) {
    __shared__ float4 kt[NBUF][TILE][32];
    __shared__ float4 vt[NBUF][TILE][32];

    const int tid = threadIdx.x;
    const int wv = tid >> 6, ln = tid & 63;
    const int row = ln & 15, qd = ln >> 4;      // phase A geometry
    const int dslot = ln & 31, hh = ln >> 5;    // phase B geometry
    const int chunk = blockIdx.x >> 8;
    const int b  = (blockIdx.x >> 3) & 31;
    const int kv = blockIdx.x & 7;
    const int chunk0 = chunk * CHUNKLEN;
    const int sp = sp_ptr[0];
    const float scale = 0.08838834764831845f;   // 1/sqrt(128)
    const int bh = b * NHEADS + kv * 8 + wv;

    const float* kbase = kcache + (size_t)(b * NKV + kv) * PADLEN * HD;
    const float* vbase = vcache + (size_t)(b * NKV + kv) * PADLEN * HD;
    const float* knew  = kr   + (size_t)(b * NKV + kv) * HD;
    const float* vnw   = vnew + (size_t)(b * NKV + kv) * HD;

    float4 qreg[8];
    {
        const float4* qsrc = (const float4*)(qr + (size_t)bh * HD) + qd * 8;
#pragma unroll
        for (int i = 0; i < 8; ++i) qreg[i] = qsrc[i];
    }

    const int sr  = wv * 2 + (ln >> 5);    // staging row 0..15
    const int sj  = ln & 31;
    const int sjk = sj ^ (sr & 7);         // K slot (pre-swizzled src)

    float m_run = -1e30f, dsum = 0.f;
    float4 acc = make_float4(0.f, 0.f, 0.f, 0.f);

    int valid = sp + 1 - chunk0;
    int nt = valid <= 0 ? 0 : (valid + TILE - 1) >> 4;
    if (nt > CHUNKLEN / TILE) nt = CHUNKLEN / TILE;

    auto stage = [&](int ts, int slot) {
        const int gl = chunk0 + (ts << 4) + sr;
        const float* krow = (gl == sp) ? knew : (kbase + (size_t)gl * HD);
        const float* vrow = (gl == sp) ? vnw  : (vbase + (size_t)gl * HD);
        gld16(krow + (sjk << 2), (float*)&kt[slot][0][0] + wv * 256);
        gld16(vrow + (sj  << 2), (float*)&vt[slot][0][0] + wv * 256);
    };

    auto compute = [&](int t) {
        const float4 (*kt_)[32] = kt[t & 3];
        const float4 (*vt_)[32] = vt[t & 3];
        float sh = 0.f;
#pragma unroll
        for (int jj = 0; jj < 8; ++jj) {
            float4 kk = kt_[row][(qd * 8 + jj) ^ (row & 7)];
            float4 qq = qreg[jj];
            sh = fmaf(qq.x, kk.x, sh);
            sh = fmaf(qq.y, kk.y, sh);
            sh = fmaf(qq.z, kk.z, sh);
            sh = fmaf(qq.w, kk.w, sh);
        }
        sh += __shfl_xor(sh, 16);
        sh += __shfl_xor(sh, 32);
        float s0 = sh * scale;
        const int l0 = chunk0 + (t << 4) + row;
        const bool dead = l0 > sp;
        if (dead) s0 = -1e30f;

        float mt = s0;
        mt = fmaxf(mt, __shfl_xor(mt, 1));
        mt = fmaxf(mt, __shfl_xor(mt, 2));
        mt = fmaxf(mt, __shfl_xor(mt, 4));
        mt = fmaxf(mt, __shfl_xor(mt, 8));
        float mnew = fmaxf(m_run, mt);
        float f = __expf(m_run - mnew);
        float p0 = dead ? 0.f : __expf(s0 - mnew);
        m_run = mnew;
        dsum = dsum * f + p0;
        acc.x *= f; acc.y *= f; acc.z *= f; acc.w *= f;

#pragma unroll
        for (int i = 0; i < 8; ++i) {
            float4 vv = vt_[hh * 8 + i][dslot];
            float pa = readlane_f(p0, i);
            float pb = readlane_f(p0, 8 + i);
            float pr = hh ? pb : pa;
            acc.x = fmaf(pr, vv.x, acc.x);
            acc.y = fmaf(pr, vv.y, acc.y);
            acc.z = fmaf(pr, vv.z, acc.z);
            acc.w = fmaf(pr, vv.w, acc.w);
        }
    };

    if (nt > 0) {
        stage(0, 0);
        stage(nt > 1 ? 1 : 0, 1);
        for (int t = 0; t < nt; ++t) {
            int ts = t + 2 < nt ? t + 2 : nt - 1;    // clamped dummy keeps counts uniform
            stage(ts, (t + 2) & 3);
            asm volatile("s_waitcnt vmcnt(4)" ::: "memory");
            __builtin_amdgcn_s_barrier();
            compute(t);
        }
    }

    acc.x += __shfl_xor(acc.x, 32);
    acc.y += __shfl_xor(acc.y, 32);
    acc.z += __shfl_xor(acc.z, 32);
    acc.w += __shfl_xor(acc.w, 32);
    float dd = dsum;
    dd += __shfl_xor(dd, 1);
    dd += __shfl_xor(dd, 2);
    dd += __shfl_xor(dd, 4);
    dd += __shfl_xor(dd, 8);

    if (hh == 0)
        *(float4*)(part_acc + ((size_t)chunk * (BATCH * NHEADS) + bh) * HD + dslot * 4) = acc;
    if (ln == 0) {
        float2 md = make_float2(m_run, dd);
        *(float2*)(part_md + ((size_t)chunk * (BATCH * NHEADS) + bh) * 2) = md;
    }
}

// merge the NCHUNK split-KV partials per head; emit bf16 hi/lo directly
__global__ __launch_bounds__(128) void attn_combine_cvt(
        const float* __restrict__ part_acc, const float* __restrict__ part_md,
        short* __restrict__ ahi, short* __restrict__ alo) {
    const int bh = blockIdx.x;
    const int d = threadIdx.x;
    float m[NCHUNK], dd[NCHUNK];
    float M = -1e30f;
#pragma unroll
    for (int c = 0; c < NCHUNK; ++c) {
        m[c]  = part_md[((size_t)c * (BATCH * NHEADS) + bh) * 2];
        dd[c] = part_md[((size_t)c * (BATCH * NHEADS) + bh) * 2 + 1];
        M = fmaxf(M, m[c]);
    }
    float D = 0.f, o = 0.f;
#pragma unroll
    for (int c = 0; c < NCHUNK; ++c) {
        float w = __expf(m[c] - M);
        D += dd[c] * w;
        o += part_acc[((size_t)c * (BATCH * NHEADS) + bh) * HD + d] * w;
    }
    float v = o / D;
    short h = f2bf(v);
    ahi[(size_t)bh * HD + d] = h;
    alo[(size_t)bh * HD + d] = f2bf(v - bf2f(h));
}

// ---------------------------------------------------------------------------
extern "C" void kernel_launch(void* const* d_in, const int* in_sizes, int n_in,
                              void* d_out, int out_size, void* d_ws, size_t ws_size,
                              hipStream_t stream) {
    const float* x   = (const float*)d_in[0];
    const float* wq  = (const float*)d_in[1];
    const float* wk  = (const float*)d_in[2];
    const float* wv  = (const float*)d_in[3];
    const float* wo  = (const float*)d_in[4];
    const float* rot = (const float*)d_in[5];
    const float* kc  = (const float*)d_in[6];
    const float* vc  = (const float*)d_in[7];
    const int*   sp  = (const int*)d_in[8];
    float* out = (float*)d_out;

    float* ws = (float*)d_ws;
    float* v_buf    = ws;                    // 32768
    float* qr_buf   = ws + 327680;           // 262144
    float* kr_buf   = ws + 589824;           // 32768
    short* xhi      = (short*)(ws + 884736);           // bf16 halves
    short* xlo      = (short*)(ws + 884736 + 131072);
    short* ahi      = (short*)(ws + 884736 + 262144);
    short* alo      = (short*)(ws + 884736 + 393216);
    float* P        = ws + 884736 + 524288;  // 16 * 327680 partials
    // split-KV partials overlay P (P consumed before attn, reused after)
    float* part_acc = P;                     // 8*2048*128 = 2097152
    float* part_md  = P + 2097152;           // 8*2048*2   = 32768

    // QKV projection: split x -> MFMA GEMM (k-split partials) -> fused reduce+rotary
    cvt_split<<<(QSEC / 4 + 255) / 256, 256, 0, stream>>>(x, xhi, xlo, QSEC / 4);
    gemm_mfma<<<dim3(160, NSPLIT), 256, 0, stream>>>(xhi, xlo, wq, wk, wv, P, QKV_STRIDE);
    reduce_rotary<<<160, 128, 0, stream>>>(P, rot, qr_buf, kr_buf, v_buf);

    // attention (split-KV x8) + fused combine/cvt
    attn_decode<<<NCHUNK * BATCH * NKV, 512, 0, stream>>>(
        qr_buf, kr_buf, v_buf, kc, vc, sp, part_acc, part_md);
    attn_combine_cvt<<<BATCH * NHEADS, 128, 0, stream>>>(part_acc, part_md, ahi, alo);

    // output projection: MFMA GEMM -> reduce into d_out
    gemm_mfma<<<dim3(128, NSPLIT), 256, 0, stream>>>(ahi, alo, wo, wo, wo, P, QSEC);
    reduce_split<<<(QSEC / 4 + 255) / 256, 256, 0, stream>>>(P, out, QSEC, QSEC);
}

// Round 11
// 341.749 us; speedup vs baseline: 1.1746x; 1.1746x over previous
//
#include <hip/hip_runtime.h>
#include <hip/hip_bf16.h>

#define HIDDEN 8192
#define NHEADS 64
#define NKV 8
#define HD 128
#define BATCH 32
#define PADLEN 2048
#define NCHUNK 8
#define CHUNKLEN 256

using bf16x8 = __attribute__((ext_vector_type(8))) short;
using f32x4 = __attribute__((ext_vector_type(4))) float;

// ---------------------------------------------------------------------------
// helpers
// ---------------------------------------------------------------------------
__device__ __forceinline__ void gld16(const float* g, float* l) {
    __builtin_amdgcn_global_load_lds(
        (const __attribute__((address_space(1))) void*)g,
        (__attribute__((address_space(3))) void*)l,
        16, 0, 0);
}

// readlane for float: bitcast, NOT value conversion (builtin is (uint,uint)!)
__device__ __forceinline__ float readlane_f(float v, int lane) {
    return __uint_as_float(__builtin_amdgcn_readlane(__float_as_uint(v), lane));
}

__device__ __forceinline__ short f2bf(float f) {      // RNE f32->bf16
    unsigned u = __float_as_uint(f);
    u += 0x7fff + ((u >> 16) & 1);
    return (short)(u >> 16);
}
__device__ __forceinline__ float bf2f(short s) {
    return __uint_as_float(((unsigned)(unsigned short)s) << 16);
}

// ---------------------------------------------------------------------------
// split a f32 vector into hi/lo bf16 (x = hi + lo, residual ~2^-17 rel)
// ---------------------------------------------------------------------------
__global__ __launch_bounds__(256) void cvt_split(const float* __restrict__ in,
                                                 short* __restrict__ hi,
                                                 short* __restrict__ lo, int n4) {
    int i = blockIdx.x * 256 + threadIdx.x;
    if (i >= n4) return;
    float4 v = ((const float4*)in)[i];
    short4 h, l;
    h.x = f2bf(v.x); l.x = f2bf(v.x - bf2f(h.x));
    h.y = f2bf(v.y); l.y = f2bf(v.y - bf2f(h.y));
    h.z = f2bf(v.z); l.z = f2bf(v.z - bf2f(h.z));
    h.w = f2bf(v.w); l.w = f2bf(v.w - bf2f(h.w));
    ((short4*)hi)[i] = h;
    ((short4*)lo)[i] = l;
}

// ---------------------------------------------------------------------------
// MFMA split-bf16 skinny GEMM v4 — ping-pong pipeline, balanced occupancy.
// r10 lesson: launch_bounds(256,6) -> 32 VGPR -> serialized loads -> 166 us.
// r9 lesson: end-of-loop register copies collapse prefetch depth.
// Here: 32 cols/wave (r7 geometry), two NAMED register sets alternating in a
// two-step unrolled loop (no copies), launch_bounds(256,4) -> <=128 VGPR
// (~100 used) -> 4 waves/SIMD with a full load-step in flight.
// ---------------------------------------------------------------------------
#define QSEC 262144          // 32*8192
#define KSEC 294912          // QSEC + 32*1024
#define QKV_STRIDE 327680    // QSEC + 2*32*1024
#define NSPLIT 16
#define KSLICE 512           // HIDDEN / NSPLIT

__global__ __launch_bounds__(256, 4) void gemm_mfma(
        const short* __restrict__ xhi, const short* __restrict__ xlo,
        const float* __restrict__ W0, const float* __restrict__ W1,
        const float* __restrict__ W2, float* __restrict__ P, size_t pstride) {
    const int tid = threadIdx.x;
    const int wv = tid >> 6, ln = tid & 63;
    const int cb = blockIdx.x, kb = blockIdx.y;

    const float* W; int N2; size_t so; int nbase;
    if (cb < 64)      { W = W0; N2 = 8192; so = 0;    nbase = cb * 128; }
    else if (cb < 72) { W = W1; N2 = 1024; so = QSEC; nbase = (cb - 64) * 128; }
    else              { W = W2; N2 = 1024; so = KSEC; nbase = (cb - 72) * 128; }

    const int n0 = nbase + wv * 32;      // this wave: cols n0..n0+31
    const int lrow = ln & 15;
    const int kgrp = ln >> 4;
    const int k0 = kb * KSLICE;

    const float* wp0 = W + (size_t)(k0 + kgrp * 8) * N2 + (n0 + lrow);
    const float* wp1 = wp0 + 16;
    const short* xh0 = xhi + (size_t)lrow * HIDDEN + k0 + kgrp * 8;
    const short* xl0 = xlo + (size_t)lrow * HIDDEN + k0 + kgrp * 8;
    const short* xh1 = xh0 + (size_t)16 * HIDDEN;
    const short* xl1 = xl0 + (size_t)16 * HIDDEN;

    f32x4 acc00 = {0.f,0.f,0.f,0.f}, acc01 = {0.f,0.f,0.f,0.f};
    f32x4 acc10 = {0.f,0.f,0.f,0.f}, acc11 = {0.f,0.f,0.f,0.f};

    // two named register sets (ping-pong, no copies)
    float cB0[8], cB1[8], dB0[8], dB1[8];
    bf16x8 cA0h, cA0l, cA1h, cA1l, dA0h, dA0l, dA1h, dA1l;

    auto loadB = [&](int kk, float (&b0)[8], float (&b1)[8]) {
#pragma unroll
        for (int j = 0; j < 8; ++j) {
            b0[j] = wp0[(size_t)(kk + j) * N2];
            b1[j] = wp1[(size_t)(kk + j) * N2];
        }
    };
    auto loadA = [&](int kk, bf16x8& h0, bf16x8& l0, bf16x8& h1, bf16x8& l1) {
        h0 = *(const bf16x8*)(xh0 + kk);
        l0 = *(const bf16x8*)(xl0 + kk);
        h1 = *(const bf16x8*)(xh1 + kk);
        l1 = *(const bf16x8*)(xl1 + kk);
    };
    auto domfma = [&](float (&b0)[8], float (&b1)[8],
                      bf16x8 ah0, bf16x8 al0, bf16x8 ah1, bf16x8 al1) {
        bf16x8 bh0, bl0, bh1, bl1;
#pragma unroll
        for (int j = 0; j < 8; ++j) {
            short h0 = f2bf(b0[j]); bh0[j] = h0; bl0[j] = f2bf(b0[j] - bf2f(h0));
            short h1 = f2bf(b1[j]); bh1[j] = h1; bl1[j] = f2bf(b1[j] - bf2f(h1));
        }
        acc00 = __builtin_amdgcn_mfma_f32_16x16x32_bf16(ah0, bh0, acc00, 0, 0, 0);
        acc10 = __builtin_amdgcn_mfma_f32_16x16x32_bf16(ah1, bh0, acc10, 0, 0, 0);
        acc01 = __builtin_amdgcn_mfma_f32_16x16x32_bf16(ah0, bh1, acc01, 0, 0, 0);
        acc11 = __builtin_amdgcn_mfma_f32_16x16x32_bf16(ah1, bh1, acc11, 0, 0, 0);
        acc00 = __builtin_amdgcn_mfma_f32_16x16x32_bf16(al0, bh0, acc00, 0, 0, 0);
        acc10 = __builtin_amdgcn_mfma_f32_16x16x32_bf16(al1, bh0, acc10, 0, 0, 0);
        acc01 = __builtin_amdgcn_mfma_f32_16x16x32_bf16(al0, bh1, acc01, 0, 0, 0);
        acc11 = __builtin_amdgcn_mfma_f32_16x16x32_bf16(al1, bh1, acc11, 0, 0, 0);
        acc00 = __builtin_amdgcn_mfma_f32_16x16x32_bf16(ah0, bl0, acc00, 0, 0, 0);
        acc10 = __builtin_amdgcn_mfma_f32_16x16x32_bf16(ah1, bl0, acc10, 0, 0, 0);
        acc01 = __builtin_amdgcn_mfma_f32_16x16x32_bf16(ah0, bl1, acc01, 0, 0, 0);
        acc11 = __builtin_amdgcn_mfma_f32_16x16x32_bf16(ah1, bl1, acc11, 0, 0, 0);
    };

    loadB(0, cB0, cB1);
    loadA(0, cA0h, cA0l, cA1h, cA1l);
#pragma unroll
    for (int kk = 0; kk < KSLICE; kk += 64) {
        // issue next-step loads (d-set) before computing c-set
        loadB(kk + 32, dB0, dB1);
        loadA(kk + 32, dA0h, dA0l, dA1h, dA1l);
        domfma(cB0, cB1, cA0h, cA0l, cA1h, cA1l);
        if (kk + 64 < KSLICE) {
            loadB(kk + 64, cB0, cB1);
            loadA(kk + 64, cA0h, cA0l, cA1h, cA1l);
        }
        domfma(dB0, dB1, dA0h, dA0l, dA1h, dA1l);
    }

    // C/D: col = l&15, row = (l>>4)*4 + reg (m89-verified)
    float* pb = P + (size_t)kb * pstride + so;
#pragma unroll
    for (int r = 0; r < 4; ++r) {
        int row = kgrp * 4 + r;
        pb[(size_t)row * N2 + n0 + lrow]              = acc00[r];
        pb[(size_t)row * N2 + n0 + 16 + lrow]         = acc01[r];
        pb[(size_t)(row + 16) * N2 + n0 + lrow]       = acc10[r];
        pb[(size_t)(row + 16) * N2 + n0 + 16 + lrow]  = acc11[r];
    }
}

// out[i] = sum_s P[s][i]  (NSPLIT k-split partials) — used for wo only
__global__ __launch_bounds__(256) void reduce_split(const float* __restrict__ P,
                                                    float* __restrict__ out,
                                                    int nelem, size_t pstride) {
    int i = (blockIdx.x * 256 + threadIdx.x) * 4;
    if (i >= nelem) return;
    float4 a = *(const float4*)(P + i);
#pragma unroll 4
    for (int s = 1; s < NSPLIT; ++s) {
        float4 b = *(const float4*)(P + (size_t)s * pstride + i);
        a.x += b.x; a.y += b.y; a.z += b.z; a.w += b.w;
    }
    *(float4*)(out + i) = a;
}

// ---------------------------------------------------------------------------
// Fused reduce(QKV partials) + rotary.
// Blocks 0..143: rot rows (q: 0..2047, k: 2048..2303) -> qr_buf/kr_buf.
// Blocks 144..159: v rows (256) -> v_buf (reduce only).
// ---------------------------------------------------------------------------
#define RROWS 16
__global__ __launch_bounds__(128) void reduce_rotary(const float* __restrict__ P,
                                                     const float* __restrict__ rot,
                                                     float* __restrict__ qout,
                                                     float* __restrict__ kout,
                                                     float* __restrict__ vout) {
    __shared__ float rows[RROWS][HD];
    const int tid = threadIdx.x;
    const int blk = blockIdx.x;

    if (blk < 144) {
        const int row0 = blk * RROWS;
        for (int i = tid; i < RROWS * HD; i += 128) {
            int r = row0 + (i >> 7);
            int d = i & 127;
            size_t off;
            if (r < BATCH * NHEADS) off = (size_t)(r >> 6) * 8192 + (r & 63) * 128 + d;
            else {
                int r2 = r - BATCH * NHEADS;
                off = QSEC + (size_t)(r2 >> 3) * 1024 + (r2 & 7) * 128 + d;
            }
            float a = P[off];
#pragma unroll 5
            for (int s = 1; s < NSPLIT; ++s) a += P[(size_t)s * QKV_STRIDE + off];
            rows[i >> 7][d] = a;
        }
        __syncthreads();

        float acc[RROWS];
#pragma unroll
        for (int r = 0; r < RROWS; ++r) acc[r] = 0.f;
        for (int d4 = 0; d4 < HD; d4 += 4) {
            float r0 = rot[(size_t)(d4 + 0) * HD + tid];
            float r1 = rot[(size_t)(d4 + 1) * HD + tid];
            float r2 = rot[(size_t)(d4 + 2) * HD + tid];
            float r3 = rot[(size_t)(d4 + 3) * HD + tid];
#pragma unroll
            for (int r = 0; r < RROWS; ++r) {
                float4 xv = *(const float4*)&rows[r][d4];
                acc[r] = fmaf(xv.x, r0, acc[r]);
                acc[r] = fmaf(xv.y, r1, acc[r]);
                acc[r] = fmaf(xv.z, r2, acc[r]);
                acc[r] = fmaf(xv.w, r3, acc[r]);
            }
        }
#pragma unroll
        for (int r = 0; r < RROWS; ++r) {
            int gr = row0 + r;
            float* dst = (gr < BATCH * NHEADS)
                             ? (qout + (size_t)gr * HD)
                             : (kout + (size_t)(gr - BATCH * NHEADS) * HD);
            dst[tid] = acc[r];
        }
    } else {
        const int row0 = (blk - 144) * RROWS;     // 0..255
        for (int i = tid; i < RROWS * HD; i += 128) {
            int r2 = row0 + (i >> 7);
            int d = i & 127;
            size_t off = KSEC + (size_t)(r2 >> 3) * 1024 + (r2 & 7) * 128 + d;
            float a = P[off];
#pragma unroll 5
            for (int s = 1; s < NSPLIT; ++s) a += P[(size_t)s * QKV_STRIDE + off];
            vout[(size_t)r2 * HD + d] = a;
        }
    }
}

// ---------------------------------------------------------------------------
// Flash-decode attention, split-KV x8, counted-vmcnt ring (T4).
// r5-proven structure (K+V staged, TILE=16, NBUF=4, vmcnt(4) depth-2);
// NCHUNK=8 -> 2048 blocks = 8 slots/CU for cross-block latency cover.
// ---------------------------------------------------------------------------
#define TILE 16
#define NBUF 4
__global__ __launch_bounds__(512, 4) void attn_decode(
        const float* __restrict__ qr, const float* __restrict__ kr,
        const float* __restrict__ vnew, const float* __restrict__ kcache,
        const float* __restrict__ vcache, const int* __restrict__ sp_ptr,
        float* __restrict__ part_acc, float* __restrict__ part_md) {
    __shared__ float4 kt[NBUF][TILE][32];
    __shared__ float4 vt[NBUF][TILE][32];

    const int tid = threadIdx.x;
    const int wv = tid >> 6, ln = tid & 63;
    const int row = ln & 15, qd = ln >> 4;      // phase A geometry
    const int dslot = ln & 31, hh = ln >> 5;    // phase B geometry
    const int chunk = blockIdx.x >> 8;
    const int b  = (blockIdx.x >> 3) & 31;
    const int kv = blockIdx.x & 7;
    const int chunk0 = chunk * CHUNKLEN;
    const int sp = sp_ptr[0];
    const float scale = 0.08838834764831845f;   // 1/sqrt(128)
    const int bh = b * NHEADS + kv * 8 + wv;

    const float* kbase = kcache + (size_t)(b * NKV + kv) * PADLEN * HD;
    const float* vbase = vcache + (size_t)(b * NKV + kv) * PADLEN * HD;
    const float* knew  = kr   + (size_t)(b * NKV + kv) * HD;
    const float* vnw   = vnew + (size_t)(b * NKV + kv) * HD;

    float4 qreg[8];
    {
        const float4* qsrc = (const float4*)(qr + (size_t)bh * HD) + qd * 8;
#pragma unroll
        for (int i = 0; i < 8; ++i) qreg[i] = qsrc[i];
    }

    const int sr  = wv * 2 + (ln >> 5);    // staging row 0..15
    const int sj  = ln & 31;
    const int sjk = sj ^ (sr & 7);         // K slot (pre-swizzled src)

    float m_run = -1e30f, dsum = 0.f;
    float4 acc = make_float4(0.f, 0.f, 0.f, 0.f);

    int valid = sp + 1 - chunk0;
    int nt = valid <= 0 ? 0 : (valid + TILE - 1) >> 4;
    if (nt > CHUNKLEN / TILE) nt = CHUNKLEN / TILE;

    auto stage = [&](int ts, int slot) {
        const int gl = chunk0 + (ts << 4) + sr;
        const float* krow = (gl == sp) ? knew : (kbase + (size_t)gl * HD);
        const float* vrow = (gl == sp) ? vnw  : (vbase + (size_t)gl * HD);
        gld16(krow + (sjk << 2), (float*)&kt[slot][0][0] + wv * 256);
        gld16(vrow + (sj  << 2), (float*)&vt[slot][0][0] + wv * 256);
    };

    auto compute = [&](int t) {
        const float4 (*kt_)[32] = kt[t & 3];
        const float4 (*vt_)[32] = vt[t & 3];
        float sh = 0.f;
#pragma unroll
        for (int jj = 0; jj < 8; ++jj) {
            float4 kk = kt_[row][(qd * 8 + jj) ^ (row & 7)];
            float4 qq = qreg[jj];
            sh = fmaf(qq.x, kk.x, sh);
            sh = fmaf(qq.y, kk.y, sh);
            sh = fmaf(qq.z, kk.z, sh);
            sh = fmaf(qq.w, kk.w, sh);
        }
        sh += __shfl_xor(sh, 16);
        sh += __shfl_xor(sh, 32);
        float s0 = sh * scale;
        const int l0 = chunk0 + (t << 4) + row;
        const bool dead = l0 > sp;
        if (dead) s0 = -1e30f;

        float mt = s0;
        mt = fmaxf(mt, __shfl_xor(mt, 1));
        mt = fmaxf(mt, __shfl_xor(mt, 2));
        mt = fmaxf(mt, __shfl_xor(mt, 4));
        mt = fmaxf(mt, __shfl_xor(mt, 8));
        float mnew = fmaxf(m_run, mt);
        float f = __expf(m_run - mnew);
        float p0 = dead ? 0.f : __expf(s0 - mnew);
        m_run = mnew;
        dsum = dsum * f + p0;
        acc.x *= f; acc.y *= f; acc.z *= f; acc.w *= f;

#pragma unroll
        for (int i = 0; i < 8; ++i) {
            float4 vv = vt_[hh * 8 + i][dslot];
            float pa = readlane_f(p0, i);
            float pb = readlane_f(p0, 8 + i);
            float pr = hh ? pb : pa;
            acc.x = fmaf(pr, vv.x, acc.x);
            acc.y = fmaf(pr, vv.y, acc.y);
            acc.z = fmaf(pr, vv.z, acc.z);
            acc.w = fmaf(pr, vv.w, acc.w);
        }
    };

    if (nt > 0) {
        stage(0, 0);
        stage(nt > 1 ? 1 : 0, 1);
        for (int t = 0; t < nt; ++t) {
            int ts = t + 2 < nt ? t + 2 : nt - 1;    // clamped dummy keeps counts uniform
            stage(ts, (t + 2) & 3);
            asm volatile("s_waitcnt vmcnt(4)" ::: "memory");
            __builtin_amdgcn_s_barrier();
            compute(t);
        }
    }

    acc.x += __shfl_xor(acc.x, 32);
    acc.y += __shfl_xor(acc.y, 32);
    acc.z += __shfl_xor(acc.z, 32);
    acc.w += __shfl_xor(acc.w, 32);
    float dd = dsum;
    dd += __shfl_xor(dd, 1);
    dd += __shfl_xor(dd, 2);
    dd += __shfl_xor(dd, 4);
    dd += __shfl_xor(dd, 8);

    if (hh == 0)
        *(float4*)(part_acc + ((size_t)chunk * (BATCH * NHEADS) + bh) * HD + dslot * 4) = acc;
    if (ln == 0) {
        float2 md = make_float2(m_run, dd);
        *(float2*)(part_md + ((size_t)chunk * (BATCH * NHEADS) + bh) * 2) = md;
    }
}

// merge the NCHUNK split-KV partials per head; emit bf16 hi/lo directly
__global__ __launch_bounds__(128) void attn_combine_cvt(
        const float* __restrict__ part_acc, const float* __restrict__ part_md,
        short* __restrict__ ahi, short* __restrict__ alo) {
    const int bh = blockIdx.x;
    const int d = threadIdx.x;
    float m[NCHUNK], dd[NCHUNK];
    float M = -1e30f;
#pragma unroll
    for (int c = 0; c < NCHUNK; ++c) {
        m[c]  = part_md[((size_t)c * (BATCH * NHEADS) + bh) * 2];
        dd[c] = part_md[((size_t)c * (BATCH * NHEADS) + bh) * 2 + 1];
        M = fmaxf(M, m[c]);
    }
    float D = 0.f, o = 0.f;
#pragma unroll
    for (int c = 0; c < NCHUNK; ++c) {
        float w = __expf(m[c] - M);
        D += dd[c] * w;
        o += part_acc[((size_t)c * (BATCH * NHEADS) + bh) * HD + d] * w;
    }
    float v = o / D;
    short h = f2bf(v);
    ahi[(size_t)bh * HD + d] = h;
    alo[(size_t)bh * HD + d] = f2bf(v - bf2f(h));
}

// ---------------------------------------------------------------------------
extern "C" void kernel_launch(void* const* d_in, const int* in_sizes, int n_in,
                              void* d_out, int out_size, void* d_ws, size_t ws_size,
                              hipStream_t stream) {
    const float* x   = (const float*)d_in[0];
    const float* wq  = (const float*)d_in[1];
    const float* wk  = (const float*)d_in[2];
    const float* wv  = (const float*)d_in[3];
    const float* wo  = (const float*)d_in[4];
    const float* rot = (const float*)d_in[5];
    const float* kc  = (const float*)d_in[6];
    const float* vc  = (const float*)d_in[7];
    const int*   sp  = (const int*)d_in[8];
    float* out = (float*)d_out;

    float* ws = (float*)d_ws;
    float* v_buf    = ws;                    // 32768
    float* qr_buf   = ws + 327680;           // 262144
    float* kr_buf   = ws + 589824;           // 32768
    short* xhi      = (short*)(ws + 884736);           // bf16 halves
    short* xlo      = (short*)(ws + 884736 + 131072);
    short* ahi      = (short*)(ws + 884736 + 262144);
    short* alo      = (short*)(ws + 884736 + 393216);
    float* P        = ws + 884736 + 524288;  // 16 * 327680 partials
    // split-KV partials overlay P (P consumed before attn, reused after)
    float* part_acc = P;                     // 8*2048*128 = 2097152
    float* part_md  = P + 2097152;           // 8*2048*2   = 32768

    // QKV projection: split x -> MFMA GEMM (k-split partials) -> fused reduce+rotary
    cvt_split<<<(QSEC / 4 + 255) / 256, 256, 0, stream>>>(x, xhi, xlo, QSEC / 4);
    gemm_mfma<<<dim3(80, NSPLIT), 256, 0, stream>>>(xhi, xlo, wq, wk, wv, P, QKV_STRIDE);
    reduce_rotary<<<160, 128, 0, stream>>>(P, rot, qr_buf, kr_buf, v_buf);

    // attention (split-KV x8) + fused combine/cvt
    attn_decode<<<NCHUNK * BATCH * NKV, 512, 0, stream>>>(
        qr_buf, kr_buf, v_buf, kc, vc, sp, part_acc, part_md);
    attn_combine_cvt<<<BATCH * NHEADS, 128, 0, stream>>>(part_acc, part_md, ahi, alo);

    // output projection: MFMA GEMM -> reduce into d_out
    gemm_mfma<<<dim3(64, NSPLIT), 256, 0, stream>>>(ahi, alo, wo, wo, wo, P, QSEC);
    reduce_split<<<(QSEC / 4 + 255) / 256, 256, 0, stream>>>(P, out, QSEC, QSEC);
}

// Round 13
// 313.199 us; speedup vs baseline: 1.2817x; 1.0912x over previous
//
#include <hip/hip_runtime.h>
#include <hip/hip_bf16.h>

#define HIDDEN 8192
#define NHEADS 64
#define NKV 8
#define HD 128
#define BATCH 32
#define PADLEN 2048
#define NCHUNK 4
#define CHUNKLEN 512

using bf16x8 = __attribute__((ext_vector_type(8))) short;
using f32x4 = __attribute__((ext_vector_type(4))) float;

// ---------------------------------------------------------------------------
// helpers
// ---------------------------------------------------------------------------
__device__ __forceinline__ void gld16(const float* g, float* l) {
    __builtin_amdgcn_global_load_lds(
        (const __attribute__((address_space(1))) void*)g,
        (__attribute__((address_space(3))) void*)l,
        16, 0, 0);
}

// readlane for float: bitcast, NOT value conversion (builtin is (uint,uint)!)
// NOTE: lane index MUST be wave-uniform (SGPR/const). Divergent index is UB —
// r12's absmax 0.078 came from readlane_f(p0, half*4+i) with divergent `half`.
__device__ __forceinline__ float readlane_f(float v, int lane) {
    return __uint_as_float(__builtin_amdgcn_readlane(__float_as_uint(v), lane));
}

__device__ __forceinline__ short f2bf(float f) {      // RNE f32->bf16
    unsigned u = __float_as_uint(f);
    u += 0x7fff + ((u >> 16) & 1);
    return (short)(u >> 16);
}
__device__ __forceinline__ float bf2f(short s) {
    return __uint_as_float(((unsigned)(unsigned short)s) << 16);
}

// ---------------------------------------------------------------------------
// split a f32 vector into hi/lo bf16 (x = hi + lo, residual ~2^-17 rel)
// ---------------------------------------------------------------------------
__global__ __launch_bounds__(256) void cvt_split(const float* __restrict__ in,
                                                 short* __restrict__ hi,
                                                 short* __restrict__ lo, int n4) {
    int i = blockIdx.x * 256 + threadIdx.x;
    if (i >= n4) return;
    float4 v = ((const float4*)in)[i];
    short4 h, l;
    h.x = f2bf(v.x); l.x = f2bf(v.x - bf2f(h.x));
    h.y = f2bf(v.y); l.y = f2bf(v.y - bf2f(h.y));
    h.z = f2bf(v.z); l.z = f2bf(v.z - bf2f(h.z));
    h.w = f2bf(v.w); l.w = f2bf(v.w - bf2f(h.w));
    ((short4*)hi)[i] = h;
    ((short4*)lo)[i] = l;
}

// ---------------------------------------------------------------------------
// MFMA split-bf16 skinny GEMM — r7-proven form (simple one-step prefetch).
// All fancier pipelining variants (depth-2, ping-pong, occupancy-squeeze)
// measured neutral-to-negative (r9/r10/r11). Do not re-pipeline.
// ---------------------------------------------------------------------------
#define QSEC 262144          // 32*8192
#define KSEC 294912          // QSEC + 32*1024
#define QKV_STRIDE 327680    // QSEC + 2*32*1024
#define NSPLIT 16
#define KSLICE 512           // HIDDEN / NSPLIT

__global__ __launch_bounds__(256) void gemm_mfma(
        const short* __restrict__ xhi, const short* __restrict__ xlo,
        const float* __restrict__ W0, const float* __restrict__ W1,
        const float* __restrict__ W2, float* __restrict__ P, size_t pstride) {
    const int tid = threadIdx.x;
    const int wv = tid >> 6, ln = tid & 63;
    const int cb = blockIdx.x, kb = blockIdx.y;

    const float* W; int N2; size_t so; int nbase;
    if (cb < 64)      { W = W0; N2 = 8192; so = 0;    nbase = cb * 128; }
    else if (cb < 72) { W = W1; N2 = 1024; so = QSEC; nbase = (cb - 64) * 128; }
    else              { W = W2; N2 = 1024; so = KSEC; nbase = (cb - 72) * 128; }

    const int n0 = nbase + wv * 32;      // this wave: cols n0..n0+31
    const int lrow = ln & 15;
    const int kgrp = ln >> 4;
    const int k0 = kb * KSLICE;

    const float* wp0 = W + (size_t)(k0 + kgrp * 8) * N2 + (n0 + lrow);
    const float* wp1 = wp0 + 16;
    const short* xh0 = xhi + (size_t)lrow * HIDDEN + k0 + kgrp * 8;
    const short* xl0 = xlo + (size_t)lrow * HIDDEN + k0 + kgrp * 8;
    const short* xh1 = xh0 + (size_t)16 * HIDDEN;
    const short* xl1 = xl0 + (size_t)16 * HIDDEN;

    f32x4 acc00 = {0.f,0.f,0.f,0.f}, acc01 = {0.f,0.f,0.f,0.f};
    f32x4 acc10 = {0.f,0.f,0.f,0.f}, acc11 = {0.f,0.f,0.f,0.f};

    float c0[8], c1[8], pb0[8], pb1[8];
    bf16x8 A0h, A0l, A1h, A1l, N0h, N0l, N1h, N1l;

    auto loadB = [&](int kk, float (&b0)[8], float (&b1)[8]) {
#pragma unroll
        for (int j = 0; j < 8; ++j) {
            b0[j] = wp0[(size_t)(kk + j) * N2];
            b1[j] = wp1[(size_t)(kk + j) * N2];
        }
    };
    auto loadA = [&](int kk, bf16x8& h0, bf16x8& l0, bf16x8& h1, bf16x8& l1) {
        h0 = *(const bf16x8*)(xh0 + kk);
        l0 = *(const bf16x8*)(xl0 + kk);
        h1 = *(const bf16x8*)(xh1 + kk);
        l1 = *(const bf16x8*)(xl1 + kk);
    };
    auto domfma = [&](float (&b0)[8], float (&b1)[8],
                      bf16x8 ah0, bf16x8 al0, bf16x8 ah1, bf16x8 al1) {
        bf16x8 bh0, bl0, bh1, bl1;
#pragma unroll
        for (int j = 0; j < 8; ++j) {
            short h0 = f2bf(b0[j]); bh0[j] = h0; bl0[j] = f2bf(b0[j] - bf2f(h0));
            short h1 = f2bf(b1[j]); bh1[j] = h1; bl1[j] = f2bf(b1[j] - bf2f(h1));
        }
        acc00 = __builtin_amdgcn_mfma_f32_16x16x32_bf16(ah0, bh0, acc00, 0, 0, 0);
        acc10 = __builtin_amdgcn_mfma_f32_16x16x32_bf16(ah1, bh0, acc10, 0, 0, 0);
        acc01 = __builtin_amdgcn_mfma_f32_16x16x32_bf16(ah0, bh1, acc01, 0, 0, 0);
        acc11 = __builtin_amdgcn_mfma_f32_16x16x32_bf16(ah1, bh1, acc11, 0, 0, 0);
        acc00 = __builtin_amdgcn_mfma_f32_16x16x32_bf16(al0, bh0, acc00, 0, 0, 0);
        acc10 = __builtin_amdgcn_mfma_f32_16x16x32_bf16(al1, bh0, acc10, 0, 0, 0);
        acc01 = __builtin_amdgcn_mfma_f32_16x16x32_bf16(al0, bh1, acc01, 0, 0, 0);
        acc11 = __builtin_amdgcn_mfma_f32_16x16x32_bf16(al1, bh1, acc11, 0, 0, 0);
        acc00 = __builtin_amdgcn_mfma_f32_16x16x32_bf16(ah0, bl0, acc00, 0, 0, 0);
        acc10 = __builtin_amdgcn_mfma_f32_16x16x32_bf16(ah1, bl0, acc10, 0, 0, 0);
        acc01 = __builtin_amdgcn_mfma_f32_16x16x32_bf16(ah0, bl1, acc01, 0, 0, 0);
        acc11 = __builtin_amdgcn_mfma_f32_16x16x32_bf16(ah1, bl1, acc11, 0, 0, 0);
    };

    loadB(0, c0, c1);
    loadA(0, A0h, A0l, A1h, A1l);
#pragma unroll
    for (int kk = 0; kk < KSLICE - 32; kk += 32) {
        loadB(kk + 32, pb0, pb1);
        loadA(kk + 32, N0h, N0l, N1h, N1l);
        domfma(c0, c1, A0h, A0l, A1h, A1l);
#pragma unroll
        for (int j = 0; j < 8; ++j) { c0[j] = pb0[j]; c1[j] = pb1[j]; }
        A0h = N0h; A0l = N0l; A1h = N1h; A1l = N1l;
    }
    domfma(c0, c1, A0h, A0l, A1h, A1l);

    // C/D: col = l&15, row = (l>>4)*4 + reg (m89-verified)
    float* pb = P + (size_t)kb * pstride + so;
#pragma unroll
    for (int r = 0; r < 4; ++r) {
        int row0 = kgrp * 4 + r;
        pb[(size_t)row0 * N2 + n0 + lrow]             = acc00[r];
        pb[(size_t)row0 * N2 + n0 + 16 + lrow]        = acc01[r];
        pb[(size_t)(row0 + 16) * N2 + n0 + lrow]      = acc10[r];
        pb[(size_t)(row0 + 16) * N2 + n0 + 16 + lrow] = acc11[r];
    }
}

// out[i] = sum_s P[s][i]  (NSPLIT k-split partials) — used for wo only
__global__ __launch_bounds__(256) void reduce_split(const float* __restrict__ P,
                                                    float* __restrict__ out,
                                                    int nelem, size_t pstride) {
    int i = (blockIdx.x * 256 + threadIdx.x) * 4;
    if (i >= nelem) return;
    float4 a = *(const float4*)(P + i);
#pragma unroll 4
    for (int s = 1; s < NSPLIT; ++s) {
        float4 b = *(const float4*)(P + (size_t)s * pstride + i);
        a.x += b.x; a.y += b.y; a.z += b.z; a.w += b.w;
    }
    *(float4*)(out + i) = a;
}

// ---------------------------------------------------------------------------
// Fused reduce(QKV partials) + rotary.
// Blocks 0..143: rot rows (q: 0..2047, k: 2048..2303) -> qr_buf/kr_buf.
// Blocks 144..159: v rows (256) -> v_buf (reduce only).
// ---------------------------------------------------------------------------
#define RROWS 16
__global__ __launch_bounds__(128) void reduce_rotary(const float* __restrict__ P,
                                                     const float* __restrict__ rot,
                                                     float* __restrict__ qout,
                                                     float* __restrict__ kout,
                                                     float* __restrict__ vout) {
    __shared__ float rows[RROWS][HD];
    const int tid = threadIdx.x;
    const int blk = blockIdx.x;

    if (blk < 144) {
        const int row0 = blk * RROWS;
        for (int i = tid; i < RROWS * HD; i += 128) {
            int r = row0 + (i >> 7);
            int d = i & 127;
            size_t off;
            if (r < BATCH * NHEADS) off = (size_t)(r >> 6) * 8192 + (r & 63) * 128 + d;
            else {
                int r2 = r - BATCH * NHEADS;
                off = QSEC + (size_t)(r2 >> 3) * 1024 + (r2 & 7) * 128 + d;
            }
            float a = P[off];
#pragma unroll 5
            for (int s = 1; s < NSPLIT; ++s) a += P[(size_t)s * QKV_STRIDE + off];
            rows[i >> 7][d] = a;
        }
        __syncthreads();

        float acc[RROWS];
#pragma unroll
        for (int r = 0; r < RROWS; ++r) acc[r] = 0.f;
        for (int d4 = 0; d4 < HD; d4 += 4) {
            float r0 = rot[(size_t)(d4 + 0) * HD + tid];
            float r1 = rot[(size_t)(d4 + 1) * HD + tid];
            float r2 = rot[(size_t)(d4 + 2) * HD + tid];
            float r3 = rot[(size_t)(d4 + 3) * HD + tid];
#pragma unroll
            for (int r = 0; r < RROWS; ++r) {
                float4 xv = *(const float4*)&rows[r][d4];
                acc[r] = fmaf(xv.x, r0, acc[r]);
                acc[r] = fmaf(xv.y, r1, acc[r]);
                acc[r] = fmaf(xv.z, r2, acc[r]);
                acc[r] = fmaf(xv.w, r3, acc[r]);
            }
        }
#pragma unroll
        for (int r = 0; r < RROWS; ++r) {
            int gr = row0 + r;
            float* dst = (gr < BATCH * NHEADS)
                             ? (qout + (size_t)gr * HD)
                             : (kout + (size_t)(gr - BATCH * NHEADS) * HD);
            dst[tid] = acc[r];
        }
    } else {
        const int row0 = (blk - 144) * RROWS;     // 0..255
        for (int i = tid; i < RROWS * HD; i += 128) {
            int r2 = row0 + (i >> 7);
            int d = i & 127;
            size_t off = KSEC + (size_t)(r2 >> 3) * 1024 + (r2 & 7) * 128 + d;
            float a = P[off];
#pragma unroll 5
            for (int s = 1; s < NSPLIT; ++s) a += P[(size_t)s * QKV_STRIDE + off];
            vout[(size_t)r2 * HD + d] = a;
        }
    }
}

// ---------------------------------------------------------------------------
// Flash-decode attention v2 (fixed): TILE=8, 4-deep ring, 32 KB LDS ->
// 4 blocks/CU. Waves 0-3 stage K, 4-7 stage V; 1 gld16/wave/tile ->
// vmcnt(2) counted ring (T4). Phase B uses TWO UNIFORM readlanes + select
// (divergent readlane index is UB — the r12 bug).
// ---------------------------------------------------------------------------
#define TILE 8
#define NBUF 4
__global__ __launch_bounds__(512, 8) void attn_decode(
        const float* __restrict__ qr, const float* __restrict__ kr,
        const float* __restrict__ vnew, const float* __restrict__ kcache,
        const float* __restrict__ vcache, const int* __restrict__ sp_ptr,
        float* __restrict__ part_acc, float* __restrict__ part_md) {
    __shared__ float4 kt[NBUF][TILE][32];     // 16 KB
    __shared__ float4 vt[NBUF][TILE][32];     // 16 KB

    const int tid = threadIdx.x;
    const int wv = tid >> 6, ln = tid & 63;
    const int row = ln & 7, dgrp = ln >> 3;     // phase A geometry
    const int d4 = ln & 31, half = ln >> 5;     // phase B geometry
    const int chunk = blockIdx.x >> 8;
    const int b  = (blockIdx.x >> 3) & 31;
    const int kv = blockIdx.x & 7;
    const int chunk0 = chunk * CHUNKLEN;
    const int sp = sp_ptr[0];
    const float scale = 0.08838834764831845f;   // 1/sqrt(128)
    const int bh = b * NHEADS + kv * 8 + wv;

    const float* kbase = kcache + (size_t)(b * NKV + kv) * PADLEN * HD;
    const float* vbase = vcache + (size_t)(b * NKV + kv) * PADLEN * HD;
    const float* knew  = kr   + (size_t)(b * NKV + kv) * HD;
    const float* vnw   = vnew + (size_t)(b * NKV + kv) * HD;

    // q dims dgrp*16..dgrp*16+15 (4 float4 = 16 VGPR)
    float4 qreg[4];
    {
        const float4* qsrc = (const float4*)(qr + (size_t)bh * HD) + dgrp * 4;
#pragma unroll
        for (int i = 0; i < 4; ++i) qreg[i] = qsrc[i];
    }

    // staging geometry: waves 0-3 stage K rows {2wv, 2wv+1}; waves 4-7 V.
    const bool isV = wv >= 4;
    const int wks = isV ? (wv - 4) : wv;          // 0..3
    const int sr  = wks * 2 + (ln >> 5);          // row 0..7
    const int sj  = ln & 31;
    const int sjk = sj ^ sr;                      // K slot (pre-swizzled src)

    float m_run = -1e30f, dsum = 0.f;
    float4 acc = make_float4(0.f, 0.f, 0.f, 0.f);

    int valid = sp + 1 - chunk0;
    int nt = valid <= 0 ? 0 : (valid + TILE - 1) >> 3;
    if (nt > CHUNKLEN / TILE) nt = CHUNKLEN / TILE;

    auto stage = [&](int ts, int slot) {
        const int gl = chunk0 + (ts << 3) + sr;
        if (isV) {
            const float* vrow = (gl == sp) ? vnw : (vbase + (size_t)gl * HD);
            gld16(vrow + (sj << 2), (float*)&vt[slot][0][0] + wks * 256);
        } else {
            const float* krow = (gl == sp) ? knew : (kbase + (size_t)gl * HD);
            gld16(krow + (sjk << 2), (float*)&kt[slot][0][0] + wks * 256);
        }
    };

    auto compute = [&](int t) {
        const float4 (*kt_)[32] = kt[t & 3];
        const float4 (*vt_)[32] = vt[t & 3];
        // phase A: 16-dim partial dot of row `row`, dims dgrp*16..+15
        float sh = 0.f;
#pragma unroll
        for (int i = 0; i < 4; ++i) {
            float4 kk = kt_[row][(dgrp * 4 + i) ^ row];
            float4 qq = qreg[i];
            sh = fmaf(qq.x, kk.x, sh);
            sh = fmaf(qq.y, kk.y, sh);
            sh = fmaf(qq.z, kk.z, sh);
            sh = fmaf(qq.w, kk.w, sh);
        }
        sh += __shfl_xor(sh, 8);
        sh += __shfl_xor(sh, 16);
        sh += __shfl_xor(sh, 32);
        float s0 = sh * scale;
        const int l0 = chunk0 + (t << 3) + row;
        const bool dead = l0 > sp;
        if (dead) s0 = -1e30f;

        float mt = s0;
        mt = fmaxf(mt, __shfl_xor(mt, 1));
        mt = fmaxf(mt, __shfl_xor(mt, 2));
        mt = fmaxf(mt, __shfl_xor(mt, 4));
        float mnew = fmaxf(m_run, mt);
        float f = __expf(m_run - mnew);
        float p0 = dead ? 0.f : __expf(s0 - mnew);
        m_run = mnew;
        dsum = dsum * f + p0;
        acc.x *= f; acc.y *= f; acc.z *= f; acc.w *= f;

        // phase B: lane owns dims d4*4..+3 for rows half*4..half*4+3.
        // UNIFORM readlane indices (i and 4+i), divergent select AFTER.
#pragma unroll
        for (int i = 0; i < 4; ++i) {
            float4 vv = vt_[half * 4 + i][d4];
            float pa = readlane_f(p0, i);        // row i
            float pb = readlane_f(p0, 4 + i);    // row 4+i
            float pr = half ? pb : pa;
            acc.x = fmaf(pr, vv.x, acc.x);
            acc.y = fmaf(pr, vv.y, acc.y);
            acc.z = fmaf(pr, vv.z, acc.z);
            acc.w = fmaf(pr, vv.w, acc.w);
        }
    };

    if (nt > 0) {
        stage(0, 0);
        stage(nt > 1 ? 1 : 0, 1);
        for (int t = 0; t < nt; ++t) {
            int ts = t + 2 < nt ? t + 2 : nt - 1;    // clamped dummy keeps counts uniform
            stage(ts, (t + 2) & 3);
            asm volatile("s_waitcnt vmcnt(2)" ::: "memory");
            __builtin_amdgcn_s_barrier();
            compute(t);
        }
    }

    // combine the two row-halves; reduce denominator over the 8-row group
    acc.x += __shfl_xor(acc.x, 32);
    acc.y += __shfl_xor(acc.y, 32);
    acc.z += __shfl_xor(acc.z, 32);
    acc.w += __shfl_xor(acc.w, 32);
    float dd = dsum;
    dd += __shfl_xor(dd, 1);
    dd += __shfl_xor(dd, 2);
    dd += __shfl_xor(dd, 4);

    if (half == 0)
        *(float4*)(part_acc + ((size_t)chunk * (BATCH * NHEADS) + bh) * HD + d4 * 4) = acc;
    if (ln == 0) {
        float2 md = make_float2(m_run, dd);
        *(float2*)(part_md + ((size_t)chunk * (BATCH * NHEADS) + bh) * 2) = md;
    }
}

// merge the NCHUNK split-KV partials per head; emit bf16 hi/lo directly
__global__ __launch_bounds__(128) void attn_combine_cvt(
        const float* __restrict__ part_acc, const float* __restrict__ part_md,
        short* __restrict__ ahi, short* __restrict__ alo) {
    const int bh = blockIdx.x;
    const int d = threadIdx.x;
    float m[NCHUNK], dd[NCHUNK];
    float M = -1e30f;
#pragma unroll
    for (int c = 0; c < NCHUNK; ++c) {
        m[c]  = part_md[((size_t)c * (BATCH * NHEADS) + bh) * 2];
        dd[c] = part_md[((size_t)c * (BATCH * NHEADS) + bh) * 2 + 1];
        M = fmaxf(M, m[c]);
    }
    float D = 0.f, o = 0.f;
#pragma unroll
    for (int c = 0; c < NCHUNK; ++c) {
        float w = __expf(m[c] - M);
        D += dd[c] * w;
        o += part_acc[((size_t)c * (BATCH * NHEADS) + bh) * HD + d] * w;
    }
    float v = o / D;
    short h = f2bf(v);
    ahi[(size_t)bh * HD + d] = h;
    alo[(size_t)bh * HD + d] = f2bf(v - bf2f(h));
}

// ---------------------------------------------------------------------------
extern "C" void kernel_launch(void* const* d_in, const int* in_sizes, int n_in,
                              void* d_out, int out_size, void* d_ws, size_t ws_size,
                              hipStream_t stream) {
    const float* x   = (const float*)d_in[0];
    const float* wq  = (const float*)d_in[1];
    const float* wk  = (const float*)d_in[2];
    const float* wv  = (const float*)d_in[3];
    const float* wo  = (const float*)d_in[4];
    const float* rot = (const float*)d_in[5];
    const float* kc  = (const float*)d_in[6];
    const float* vc  = (const float*)d_in[7];
    const int*   sp  = (const int*)d_in[8];
    float* out = (float*)d_out;

    float* ws = (float*)d_ws;
    float* v_buf    = ws;                    // 32768
    float* qr_buf   = ws + 327680;           // 262144
    float* kr_buf   = ws + 589824;           // 32768
    short* xhi      = (short*)(ws + 884736);           // bf16 halves
    short* xlo      = (short*)(ws + 884736 + 131072);
    short* ahi      = (short*)(ws + 884736 + 262144);
    short* alo      = (short*)(ws + 884736 + 393216);
    float* P        = ws + 884736 + 524288;  // 16 * 327680 partials
    // split-KV partials overlay P (P consumed before attn, reused after)
    float* part_acc = P;                     // 4*2048*128 = 1048576
    float* part_md  = P + 1048576;           // 4*2048*2   = 16384

    // QKV projection: split x -> MFMA GEMM (k-split partials) -> fused reduce+rotary
    cvt_split<<<(QSEC / 4 + 255) / 256, 256, 0, stream>>>(x, xhi, xlo, QSEC / 4);
    gemm_mfma<<<dim3(80, NSPLIT), 256, 0, stream>>>(xhi, xlo, wq, wk, wv, P, QKV_STRIDE);
    reduce_rotary<<<160, 128, 0, stream>>>(P, rot, qr_buf, kr_buf, v_buf);

    // attention (split-KV x4, TILE=8, 4 blocks/CU) + fused combine/cvt
    attn_decode<<<NCHUNK * BATCH * NKV, 512, 0, stream>>>(
        qr_buf, kr_buf, v_buf, kc, vc, sp, part_acc, part_md);
    attn_combine_cvt<<<BATCH * NHEADS, 128, 0, stream>>>(part_acc, part_md, ahi, alo);

    // output projection: MFMA GEMM -> reduce into d_out
    gemm_mfma<<<dim3(64, NSPLIT), 256, 0, stream>>>(ahi, alo, wo, wo, wo, P, QSEC);
    reduce_split<<<(QSEC / 4 + 255) / 256, 256, 0, stream>>>(P, out, QSEC, QSEC);
}

// Round 14
// 312.949 us; speedup vs baseline: 1.2827x; 1.0008x over previous
//
#include <hip/hip_runtime.h>
#include <hip/hip_bf16.h>

#define HIDDEN 8192
#define NHEADS 64
#define NKV 8
#define HD 128
#define BATCH 32
#define PADLEN 2048
#define NCHUNK 4
#define CHUNKLEN 512

using bf16x8 = __attribute__((ext_vector_type(8))) short;
using f32x4 = __attribute__((ext_vector_type(4))) float;

// ---------------------------------------------------------------------------
// helpers
// ---------------------------------------------------------------------------
__device__ __forceinline__ void gld16(const float* g, float* l) {
    __builtin_amdgcn_global_load_lds(
        (const __attribute__((address_space(1))) void*)g,
        (__attribute__((address_space(3))) void*)l,
        16, 0, 0);
}

// readlane for float: bitcast, NOT value conversion (builtin is (uint,uint)!)
// Lane index MUST be wave-uniform (divergent index is UB — r12 lesson).
__device__ __forceinline__ float readlane_f(float v, int lane) {
    return __uint_as_float(__builtin_amdgcn_readlane(__float_as_uint(v), lane));
}

__device__ __forceinline__ short f2bf(float f) {      // RNE f32->bf16
    unsigned u = __float_as_uint(f);
    u += 0x7fff + ((u >> 16) & 1);
    return (short)(u >> 16);
}
__device__ __forceinline__ float bf2f(short s) {
    return __uint_as_float(((unsigned)(unsigned short)s) << 16);
}

// ---------------------------------------------------------------------------
// split a f32 vector into hi/lo bf16 (x = hi + lo, residual ~2^-17 rel)
// ---------------------------------------------------------------------------
__global__ __launch_bounds__(256) void cvt_split(const float* __restrict__ in,
                                                 short* __restrict__ hi,
                                                 short* __restrict__ lo, int n4) {
    int i = blockIdx.x * 256 + threadIdx.x;
    if (i >= n4) return;
    float4 v = ((const float4*)in)[i];
    short4 h, l;
    h.x = f2bf(v.x); l.x = f2bf(v.x - bf2f(h.x));
    h.y = f2bf(v.y); l.y = f2bf(v.y - bf2f(h.y));
    h.z = f2bf(v.z); l.z = f2bf(v.z - bf2f(h.z));
    h.w = f2bf(v.w); l.w = f2bf(v.w - bf2f(h.w));
    ((short4*)hi)[i] = h;
    ((short4*)lo)[i] = l;
}

// ---------------------------------------------------------------------------
// MFMA split-bf16 skinny GEMM — r7-proven form. All pipelining variants
// (depth-2, ping-pong, occupancy-squeeze) measured neutral-to-negative
// (r9/r10/r11). Do not re-pipeline.
// ---------------------------------------------------------------------------
#define QSEC 262144          // 32*8192
#define KSEC 294912          // QSEC + 32*1024
#define QKV_STRIDE 327680    // QSEC + 2*32*1024
#define NSPLIT 16
#define KSLICE 512           // HIDDEN / NSPLIT

__global__ __launch_bounds__(256) void gemm_mfma(
        const short* __restrict__ xhi, const short* __restrict__ xlo,
        const float* __restrict__ W0, const float* __restrict__ W1,
        const float* __restrict__ W2, float* __restrict__ P, size_t pstride) {
    const int tid = threadIdx.x;
    const int wv = tid >> 6, ln = tid & 63;
    const int cb = blockIdx.x, kb = blockIdx.y;

    const float* W; int N2; size_t so; int nbase;
    if (cb < 64)      { W = W0; N2 = 8192; so = 0;    nbase = cb * 128; }
    else if (cb < 72) { W = W1; N2 = 1024; so = QSEC; nbase = (cb - 64) * 128; }
    else              { W = W2; N2 = 1024; so = KSEC; nbase = (cb - 72) * 128; }

    const int n0 = nbase + wv * 32;      // this wave: cols n0..n0+31
    const int lrow = ln & 15;
    const int kgrp = ln >> 4;
    const int k0 = kb * KSLICE;

    const float* wp0 = W + (size_t)(k0 + kgrp * 8) * N2 + (n0 + lrow);
    const float* wp1 = wp0 + 16;
    const short* xh0 = xhi + (size_t)lrow * HIDDEN + k0 + kgrp * 8;
    const short* xl0 = xlo + (size_t)lrow * HIDDEN + k0 + kgrp * 8;
    const short* xh1 = xh0 + (size_t)16 * HIDDEN;
    const short* xl1 = xl0 + (size_t)16 * HIDDEN;

    f32x4 acc00 = {0.f,0.f,0.f,0.f}, acc01 = {0.f,0.f,0.f,0.f};
    f32x4 acc10 = {0.f,0.f,0.f,0.f}, acc11 = {0.f,0.f,0.f,0.f};

    float c0[8], c1[8], pb0[8], pb1[8];
    bf16x8 A0h, A0l, A1h, A1l, N0h, N0l, N1h, N1l;

    auto loadB = [&](int kk, float (&b0)[8], float (&b1)[8]) {
#pragma unroll
        for (int j = 0; j < 8; ++j) {
            b0[j] = wp0[(size_t)(kk + j) * N2];
            b1[j] = wp1[(size_t)(kk + j) * N2];
        }
    };
    auto loadA = [&](int kk, bf16x8& h0, bf16x8& l0, bf16x8& h1, bf16x8& l1) {
        h0 = *(const bf16x8*)(xh0 + kk);
        l0 = *(const bf16x8*)(xl0 + kk);
        h1 = *(const bf16x8*)(xh1 + kk);
        l1 = *(const bf16x8*)(xl1 + kk);
    };
    auto domfma = [&](float (&b0)[8], float (&b1)[8],
                      bf16x8 ah0, bf16x8 al0, bf16x8 ah1, bf16x8 al1) {
        bf16x8 bh0, bl0, bh1, bl1;
#pragma unroll
        for (int j = 0; j < 8; ++j) {
            short h0 = f2bf(b0[j]); bh0[j] = h0; bl0[j] = f2bf(b0[j] - bf2f(h0));
            short h1 = f2bf(b1[j]); bh1[j] = h1; bl1[j] = f2bf(b1[j] - bf2f(h1));
        }
        acc00 = __builtin_amdgcn_mfma_f32_16x16x32_bf16(ah0, bh0, acc00, 0, 0, 0);
        acc10 = __builtin_amdgcn_mfma_f32_16x16x32_bf16(ah1, bh0, acc10, 0, 0, 0);
        acc01 = __builtin_amdgcn_mfma_f32_16x16x32_bf16(ah0, bh1, acc01, 0, 0, 0);
        acc11 = __builtin_amdgcn_mfma_f32_16x16x32_bf16(ah1, bh1, acc11, 0, 0, 0);
        acc00 = __builtin_amdgcn_mfma_f32_16x16x32_bf16(al0, bh0, acc00, 0, 0, 0);
        acc10 = __builtin_amdgcn_mfma_f32_16x16x32_bf16(al1, bh0, acc10, 0, 0, 0);
        acc01 = __builtin_amdgcn_mfma_f32_16x16x32_bf16(al0, bh1, acc01, 0, 0, 0);
        acc11 = __builtin_amdgcn_mfma_f32_16x16x32_bf16(al1, bh1, acc11, 0, 0, 0);
        acc00 = __builtin_amdgcn_mfma_f32_16x16x32_bf16(ah0, bl0, acc00, 0, 0, 0);
        acc10 = __builtin_amdgcn_mfma_f32_16x16x32_bf16(ah1, bl0, acc10, 0, 0, 0);
        acc01 = __builtin_amdgcn_mfma_f32_16x16x32_bf16(ah0, bl1, acc01, 0, 0, 0);
        acc11 = __builtin_amdgcn_mfma_f32_16x16x32_bf16(ah1, bl1, acc11, 0, 0, 0);
    };

    loadB(0, c0, c1);
    loadA(0, A0h, A0l, A1h, A1l);
#pragma unroll
    for (int kk = 0; kk < KSLICE - 32; kk += 32) {
        loadB(kk + 32, pb0, pb1);
        loadA(kk + 32, N0h, N0l, N1h, N1l);
        domfma(c0, c1, A0h, A0l, A1h, A1l);
#pragma unroll
        for (int j = 0; j < 8; ++j) { c0[j] = pb0[j]; c1[j] = pb1[j]; }
        A0h = N0h; A0l = N0l; A1h = N1h; A1l = N1l;
    }
    domfma(c0, c1, A0h, A0l, A1h, A1l);

    // C/D: col = l&15, row = (l>>4)*4 + reg (m89-verified)
    float* pb = P + (size_t)kb * pstride + so;
#pragma unroll
    for (int r = 0; r < 4; ++r) {
        int row0 = kgrp * 4 + r;
        pb[(size_t)row0 * N2 + n0 + lrow]             = acc00[r];
        pb[(size_t)row0 * N2 + n0 + 16 + lrow]        = acc01[r];
        pb[(size_t)(row0 + 16) * N2 + n0 + lrow]      = acc10[r];
        pb[(size_t)(row0 + 16) * N2 + n0 + 16 + lrow] = acc11[r];
    }
}

// out[i] = sum_s P[s][i]  (NSPLIT k-split partials) — used for wo only
__global__ __launch_bounds__(256) void reduce_split(const float* __restrict__ P,
                                                    float* __restrict__ out,
                                                    int nelem, size_t pstride) {
    int i = (blockIdx.x * 256 + threadIdx.x) * 4;
    if (i >= nelem) return;
    float4 a = *(const float4*)(P + i);
#pragma unroll 4
    for (int s = 1; s < NSPLIT; ++s) {
        float4 b = *(const float4*)(P + (size_t)s * pstride + i);
        a.x += b.x; a.y += b.y; a.z += b.z; a.w += b.w;
    }
    *(float4*)(out + i) = a;
}

// ---------------------------------------------------------------------------
// Fused reduce(QKV partials) + rotary.
// Blocks 0..143: rot rows (q: 0..2047, k: 2048..2303) -> qr_buf/kr_buf.
// Blocks 144..159: v rows (256) -> v_buf (reduce only).
// ---------------------------------------------------------------------------
#define RROWS 16
__global__ __launch_bounds__(128) void reduce_rotary(const float* __restrict__ P,
                                                     const float* __restrict__ rot,
                                                     float* __restrict__ qout,
                                                     float* __restrict__ kout,
                                                     float* __restrict__ vout) {
    __shared__ float rows[RROWS][HD];
    const int tid = threadIdx.x;
    const int blk = blockIdx.x;

    if (blk < 144) {
        const int row0 = blk * RROWS;
        for (int i = tid; i < RROWS * HD; i += 128) {
            int r = row0 + (i >> 7);
            int d = i & 127;
            size_t off;
            if (r < BATCH * NHEADS) off = (size_t)(r >> 6) * 8192 + (r & 63) * 128 + d;
            else {
                int r2 = r - BATCH * NHEADS;
                off = QSEC + (size_t)(r2 >> 3) * 1024 + (r2 & 7) * 128 + d;
            }
            float a = P[off];
#pragma unroll 5
            for (int s = 1; s < NSPLIT; ++s) a += P[(size_t)s * QKV_STRIDE + off];
            rows[i >> 7][d] = a;
        }
        __syncthreads();

        float acc[RROWS];
#pragma unroll
        for (int r = 0; r < RROWS; ++r) acc[r] = 0.f;
        for (int d4 = 0; d4 < HD; d4 += 4) {
            float r0 = rot[(size_t)(d4 + 0) * HD + tid];
            float r1 = rot[(size_t)(d4 + 1) * HD + tid];
            float r2 = rot[(size_t)(d4 + 2) * HD + tid];
            float r3 = rot[(size_t)(d4 + 3) * HD + tid];
#pragma unroll
            for (int r = 0; r < RROWS; ++r) {
                float4 xv = *(const float4*)&rows[r][d4];
                acc[r] = fmaf(xv.x, r0, acc[r]);
                acc[r] = fmaf(xv.y, r1, acc[r]);
                acc[r] = fmaf(xv.z, r2, acc[r]);
                acc[r] = fmaf(xv.w, r3, acc[r]);
            }
        }
#pragma unroll
        for (int r = 0; r < RROWS; ++r) {
            int gr = row0 + r;
            float* dst = (gr < BATCH * NHEADS)
                             ? (qout + (size_t)gr * HD)
                             : (kout + (size_t)(gr - BATCH * NHEADS) * HD);
            dst[tid] = acc[r];
        }
    } else {
        const int row0 = (blk - 144) * RROWS;     // 0..255
        for (int i = tid; i < RROWS * HD; i += 128) {
            int r2 = row0 + (i >> 7);
            int d = i & 127;
            size_t off = KSEC + (size_t)(r2 >> 3) * 1024 + (r2 & 7) * 128 + d;
            float a = P[off];
#pragma unroll 5
            for (int s = 1; s < NSPLIT; ++s) a += P[(size_t)s * QKV_STRIDE + off];
            vout[(size_t)r2 * HD + d] = a;
        }
    }
}

// ---------------------------------------------------------------------------
// Flash-decode attention — measured-optimal config (r5/r9): TILE=16, NBUF=4
// ring, K+V staged via gld16 (2/wave/tile -> vmcnt(4) = depth-2 counted),
// NCHUNK=4. TILE=8 (+14us, r13), V-bypass (+160us, r8), NCHUNK=8 variants
// all measured worse. 64 KB LDS -> 2 blocks/CU.
// ---------------------------------------------------------------------------
#define TILE 16
#define NBUF 4
__global__ __launch_bounds__(512, 4) void attn_decode(
        const float* __restrict__ qr, const float* __restrict__ kr,
        const float* __restrict__ vnew, const float* __restrict__ kcache,
        const float* __restrict__ vcache, const int* __restrict__ sp_ptr,
        float* __restrict__ part_acc, float* __restrict__ part_md) {
    __shared__ float4 kt[NBUF][TILE][32];
    __shared__ float4 vt[NBUF][TILE][32];

    const int tid = threadIdx.x;
    const int wv = tid >> 6, ln = tid & 63;
    const int row = ln & 15, qd = ln >> 4;      // phase A geometry
    const int dslot = ln & 31, hh = ln >> 5;    // phase B geometry
    const int chunk = blockIdx.x >> 8;
    const int b  = (blockIdx.x >> 3) & 31;
    const int kv = blockIdx.x & 7;
    const int chunk0 = chunk * CHUNKLEN;
    const int sp = sp_ptr[0];
    const float scale = 0.08838834764831845f;   // 1/sqrt(128)
    const int bh = b * NHEADS + kv * 8 + wv;

    const float* kbase = kcache + (size_t)(b * NKV + kv) * PADLEN * HD;
    const float* vbase = vcache + (size_t)(b * NKV + kv) * PADLEN * HD;
    const float* knew  = kr   + (size_t)(b * NKV + kv) * HD;
    const float* vnw   = vnew + (size_t)(b * NKV + kv) * HD;

    float4 qreg[8];
    {
        const float4* qsrc = (const float4*)(qr + (size_t)bh * HD) + qd * 8;
#pragma unroll
        for (int i = 0; i < 8; ++i) qreg[i] = qsrc[i];
    }

    const int sr  = wv * 2 + (ln >> 5);    // staging row 0..15
    const int sj  = ln & 31;
    const int sjk = sj ^ (sr & 7);         // K slot (pre-swizzled src)

    float m_run = -1e30f, dsum = 0.f;
    float4 acc = make_float4(0.f, 0.f, 0.f, 0.f);

    int valid = sp + 1 - chunk0;
    int nt = valid <= 0 ? 0 : (valid + TILE - 1) >> 4;
    if (nt > CHUNKLEN / TILE) nt = CHUNKLEN / TILE;

    auto stage = [&](int ts, int slot) {
        const int gl = chunk0 + (ts << 4) + sr;
        const float* krow = (gl == sp) ? knew : (kbase + (size_t)gl * HD);
        const float* vrow = (gl == sp) ? vnw  : (vbase + (size_t)gl * HD);
        gld16(krow + (sjk << 2), (float*)&kt[slot][0][0] + wv * 256);
        gld16(vrow + (sj  << 2), (float*)&vt[slot][0][0] + wv * 256);
    };

    auto compute = [&](int t) {
        const float4 (*kt_)[32] = kt[t & 3];
        const float4 (*vt_)[32] = vt[t & 3];
        float sh = 0.f;
#pragma unroll
        for (int jj = 0; jj < 8; ++jj) {
            float4 kk = kt_[row][(qd * 8 + jj) ^ (row & 7)];
            float4 qq = qreg[jj];
            sh = fmaf(qq.x, kk.x, sh);
            sh = fmaf(qq.y, kk.y, sh);
            sh = fmaf(qq.z, kk.z, sh);
            sh = fmaf(qq.w, kk.w, sh);
        }
        sh += __shfl_xor(sh, 16);
        sh += __shfl_xor(sh, 32);
        float s0 = sh * scale;
        const int l0 = chunk0 + (t << 4) + row;
        const bool dead = l0 > sp;
        if (dead) s0 = -1e30f;

        float mt = s0;
        mt = fmaxf(mt, __shfl_xor(mt, 1));
        mt = fmaxf(mt, __shfl_xor(mt, 2));
        mt = fmaxf(mt, __shfl_xor(mt, 4));
        mt = fmaxf(mt, __shfl_xor(mt, 8));
        float mnew = fmaxf(m_run, mt);
        float f = __expf(m_run - mnew);
        float p0 = dead ? 0.f : __expf(s0 - mnew);
        m_run = mnew;
        dsum = dsum * f + p0;
        acc.x *= f; acc.y *= f; acc.z *= f; acc.w *= f;

        // phase B: UNIFORM readlane indices, divergent select after (r12 rule)
#pragma unroll
        for (int i = 0; i < 8; ++i) {
            float4 vv = vt_[hh * 8 + i][dslot];
            float pa = readlane_f(p0, i);
            float pb = readlane_f(p0, 8 + i);
            float pr = hh ? pb : pa;
            acc.x = fmaf(pr, vv.x, acc.x);
            acc.y = fmaf(pr, vv.y, acc.y);
            acc.z = fmaf(pr, vv.z, acc.z);
            acc.w = fmaf(pr, vv.w, acc.w);
        }
    };

    if (nt > 0) {
        stage(0, 0);
        stage(nt > 1 ? 1 : 0, 1);
        for (int t = 0; t < nt; ++t) {
            int ts = t + 2 < nt ? t + 2 : nt - 1;    // clamped dummy keeps counts uniform
            stage(ts, (t + 2) & 3);
            asm volatile("s_waitcnt vmcnt(4)" ::: "memory");
            __builtin_amdgcn_s_barrier();
            compute(t);
        }
    }

    acc.x += __shfl_xor(acc.x, 32);
    acc.y += __shfl_xor(acc.y, 32);
    acc.z += __shfl_xor(acc.z, 32);
    acc.w += __shfl_xor(acc.w, 32);
    float dd = dsum;
    dd += __shfl_xor(dd, 1);
    dd += __shfl_xor(dd, 2);
    dd += __shfl_xor(dd, 4);
    dd += __shfl_xor(dd, 8);

    if (hh == 0)
        *(float4*)(part_acc + ((size_t)chunk * (BATCH * NHEADS) + bh) * HD + dslot * 4) = acc;
    if (ln == 0) {
        float2 md = make_float2(m_run, dd);
        *(float2*)(part_md + ((size_t)chunk * (BATCH * NHEADS) + bh) * 2) = md;
    }
}

// merge the NCHUNK split-KV partials per head; emit bf16 hi/lo directly
__global__ __launch_bounds__(128) void attn_combine_cvt(
        const float* __restrict__ part_acc, const float* __restrict__ part_md,
        short* __restrict__ ahi, short* __restrict__ alo) {
    const int bh = blockIdx.x;
    const int d = threadIdx.x;
    float m[NCHUNK], dd[NCHUNK];
    float M = -1e30f;
#pragma unroll
    for (int c = 0; c < NCHUNK; ++c) {
        m[c]  = part_md[((size_t)c * (BATCH * NHEADS) + bh) * 2];
        dd[c] = part_md[((size_t)c * (BATCH * NHEADS) + bh) * 2 + 1];
        M = fmaxf(M, m[c]);
    }
    float D = 0.f, o = 0.f;
#pragma unroll
    for (int c = 0; c < NCHUNK; ++c) {
        float w = __expf(m[c] - M);
        D += dd[c] * w;
        o += part_acc[((size_t)c * (BATCH * NHEADS) + bh) * HD + d] * w;
    }
    float v = o / D;
    short h = f2bf(v);
    ahi[(size_t)bh * HD + d] = h;
    alo[(size_t)bh * HD + d] = f2bf(v - bf2f(h));
}

// ---------------------------------------------------------------------------
extern "C" void kernel_launch(void* const* d_in, const int* in_sizes, int n_in,
                              void* d_out, int out_size, void* d_ws, size_t ws_size,
                              hipStream_t stream) {
    const float* x   = (const float*)d_in[0];
    const float* wq  = (const float*)d_in[1];
    const float* wk  = (const float*)d_in[2];
    const float* wv  = (const float*)d_in[3];
    const float* wo  = (const float*)d_in[4];
    const float* rot = (const float*)d_in[5];
    const float* kc  = (const float*)d_in[6];
    const float* vc  = (const float*)d_in[7];
    const int*   sp  = (const int*)d_in[8];
    float* out = (float*)d_out;

    float* ws = (float*)d_ws;
    float* v_buf    = ws;                    // 32768
    float* qr_buf   = ws + 327680;           // 262144
    float* kr_buf   = ws + 589824;           // 32768
    short* xhi      = (short*)(ws + 884736);           // bf16 halves
    short* xlo      = (short*)(ws + 884736 + 131072);
    short* ahi      = (short*)(ws + 884736 + 262144);
    short* alo      = (short*)(ws + 884736 + 393216);
    float* P        = ws + 884736 + 524288;  // 16 * 327680 partials
    // split-KV partials overlay P (P consumed before attn, reused after)
    float* part_acc = P;                     // 4*2048*128 = 1048576
    float* part_md  = P + 1048576;           // 4*2048*2   = 16384

    // QKV projection: split x -> MFMA GEMM (k-split partials) -> fused reduce+rotary
    cvt_split<<<(QSEC / 4 + 255) / 256, 256, 0, stream>>>(x, xhi, xlo, QSEC / 4);
    gemm_mfma<<<dim3(80, NSPLIT), 256, 0, stream>>>(xhi, xlo, wq, wk, wv, P, QKV_STRIDE);
    reduce_rotary<<<160, 128, 0, stream>>>(P, rot, qr_buf, kr_buf, v_buf);

    // attention (split-KV x4, TILE=16) + fused combine/cvt
    attn_decode<<<NCHUNK * BATCH * NKV, 512, 0, stream>>>(
        qr_buf, kr_buf, v_buf, kc, vc, sp, part_acc, part_md);
    attn_combine_cvt<<<BATCH * NHEADS, 128, 0, stream>>>(part_acc, part_md, ahi, alo);

    // output projection: MFMA GEMM -> reduce into d_out
    gemm_mfma<<<dim3(64, NSPLIT), 256, 0, stream>>>(ahi, alo, wo, wo, wo, P, QSEC);
    reduce_split<<<(QSEC / 4 + 255) / 256, 256, 0, stream>>>(P, out, QSEC, QSEC);
}